// Round 3
// baseline (714.447 us; speedup 1.0000x reference)
//
#include <hip/hip_runtime.h>
#include <hip/hip_bf16.h>
#include <stdint.h>

// LPLRQuantizedLinear: B=8192 rows, N=M=4096, rank 64 (48 frozen + 16 ft).
// ALL float tensors are FP32 (per reference); Q_idxs int32; output FP32.
//
// Pipeline:
//   prep     : R_cat[64][4096] bf16 (ws), L_cat -> Wq[:, 4096:4160] bf16
//   decode   : Wq[:, :4096] = bf16(0.02 * grid[Q_idxs])      (f32 grid)
//   fwht_pre : h[:, :4096] = bf16(FWHT(x*SU)/64)             (f32 in, fp32 math)
//   tgemm    : Tpart = h @ R_cat^T (k-split 4, fp32 partials)
//   tconv    : h[:, 4096:4160] = bf16(sum Tpart)
//   mgemm    : d_out = f32( h[8192,4160] @ Wq[4096,4160]^T ) -- 256^2 1-barrier/K-step
//   fwht_post: d_out = (FWHT(d_out)/64) * SV                 (f32 in-place)
//
// mgemm v3: v2b measured 283us, MfmaUtil 43%, bank-conflicts 0. Per-K-step
// cycle count (2612) == LDS floor (~1100) + MFMA floor (~1250) SERIAL: the
// 4-barrier phase structure alternated the pipes. v3 keeps the verified
// swizzle/staging/vmcnt accounting but collapses to ONE barrier per K-step
// so ds_read (LDS pipe) and MFMA (matrix pipe) overlap via compiler lgkmcnt
// scheduling + cross-wave co-issue. Safety: vmcnt(8)+bar at end of iter i
// guarantees slot i+1 landed collectively; stage at iter i targets slot
// (i-1)&3 whose reads were lgkm-drained before bar(i-1).

typedef __bf16 bf16;
typedef __bf16 bf16x8 __attribute__((ext_vector_type(8)));
typedef float f32x4 __attribute__((ext_vector_type(4)));

#define KE 4160
#define NN 4096
#define MM 4096
#define BB 8192

// ---------------- prep: build R_cat (bf16) and L columns of Wq ----------------
__global__ void prep_kernel(const float* __restrict__ Lft, const float* __restrict__ Rft,
                            const float* __restrict__ Lres, const float* __restrict__ Rres,
                            bf16* __restrict__ Rcat, bf16* __restrict__ Wq) {
  int tid = blockIdx.x * 256 + threadIdx.x;   // 524288 total
  if (tid < 64 * 4096) {
    int r = tid >> 12, n = tid & 4095;
    float v = (r < 48) ? Rres[r * 4096 + n] : Rft[(r - 48) * 4096 + n];
    Rcat[tid] = (bf16)v;
  } else {
    int t2 = tid - 64 * 4096;
    int m = t2 >> 6, r = t2 & 63;
    float v = (r < 48) ? Lres[m * 48 + r] : Lft[m * 16 + (r - 48)];
    Wq[(size_t)m * KE + 4096 + r] = (bf16)v;
  }
}

// ---------------- decode: Wq[:, :4096] = bf16(0.02*grid[Q_idxs]) ----------------
__global__ void decode_kernel(const int* __restrict__ qidx, const float* __restrict__ grid,
                              bf16* __restrict__ Wq) {
  int tid = blockIdx.x * 256 + threadIdx.x;   // 4096*512 = 2M
  int m = tid >> 9, g = tid & 511;
  uint32_t idx = (uint32_t)qidx[tid];
  const float4* gp = (const float4*)(grid + (size_t)idx * 8);
  float4 w0 = gp[0], w1 = gp[1];
  bf16x8 o;
  o[0] = (bf16)(w0.x * 0.02f); o[1] = (bf16)(w0.y * 0.02f);
  o[2] = (bf16)(w0.z * 0.02f); o[3] = (bf16)(w0.w * 0.02f);
  o[4] = (bf16)(w1.x * 0.02f); o[5] = (bf16)(w1.y * 0.02f);
  o[6] = (bf16)(w1.z * 0.02f); o[7] = (bf16)(w1.w * 0.02f);
  *(bf16x8*)(Wq + (size_t)m * KE + g * 8) = o;
}

// LDS skew for the FWHT butterflies: pure storage permutation, breaks the
// power-of-2 bank aliasing of the strided stages (+1 bank per 32 words).
#define SK(i) ((i) + ((i) >> 5))

// ---------------- FWHT-4096 row-wise, f32 in -> bf16 out (pre, *SU before) ----------------
__global__ void fwht_pre_kernel(const float* __restrict__ src,
                                bf16* __restrict__ dst,
                                const float* __restrict__ SU) {
  __shared__ float buf[4224];
  const int row = blockIdx.x, t = threadIdx.x;
  const float4* sp = (const float4*)(src + (size_t)row * NN + t * 16);
  const float4* su = (const float4*)(SU + t * 16);
  float v[16];
#pragma unroll
  for (int q = 0; q < 4; ++q) {
    float4 a = sp[q], s = su[q];
    v[q * 4 + 0] = a.x * s.x; v[q * 4 + 1] = a.y * s.y;
    v[q * 4 + 2] = a.z * s.z; v[q * 4 + 3] = a.w * s.w;
  }
#pragma unroll
  for (int s = 1; s < 16; s <<= 1) {
#pragma unroll
    for (int i = 0; i < 16; ++i) {
      if (!(i & s)) { float a = v[i], b = v[i + s]; v[i] = a + b; v[i + s] = a - b; }
    }
  }
#pragma unroll
  for (int i = 0; i < 16; ++i) buf[SK(t * 16 + i)] = v[i];
  for (int s = 16; s < 4096; s <<= 1) {
    __syncthreads();
#pragma unroll
    for (int j = 0; j < 8; ++j) {
      int p = t + j * 256;
      int i = ((p & ~(s - 1)) << 1) | (p & (s - 1));
      float a = buf[SK(i)], b = buf[SK(i + s)];
      buf[SK(i)] = a + b; buf[SK(i + s)] = a - b;
    }
  }
  __syncthreads();
  bf16x8 o0, o1;
#pragma unroll
  for (int i = 0; i < 8; ++i) {
    o0[i] = (bf16)(buf[SK(t * 16 + i)] * 0.015625f);
    o1[i] = (bf16)(buf[SK(t * 16 + 8 + i)] * 0.015625f);
  }
  bf16* dp = dst + (size_t)row * KE + t * 16;
  *(bf16x8*)dp = o0;
  *(bf16x8*)(dp + 8) = o1;
}

// ---------------- FWHT-4096 row-wise, f32 in-place (post, *SV after) ----------------
__global__ void fwht_post_kernel(float* __restrict__ data, const float* __restrict__ SV) {
  __shared__ float buf[4224];
  const int row = blockIdx.x, t = threadIdx.x;
  float4* dp = (float4*)(data + (size_t)row * MM + t * 16);
  float v[16];
#pragma unroll
  for (int q = 0; q < 4; ++q) {
    float4 a = dp[q];
    v[q * 4 + 0] = a.x; v[q * 4 + 1] = a.y; v[q * 4 + 2] = a.z; v[q * 4 + 3] = a.w;
  }
#pragma unroll
  for (int s = 1; s < 16; s <<= 1) {
#pragma unroll
    for (int i = 0; i < 16; ++i) {
      if (!(i & s)) { float a = v[i], b = v[i + s]; v[i] = a + b; v[i + s] = a - b; }
    }
  }
#pragma unroll
  for (int i = 0; i < 16; ++i) buf[SK(t * 16 + i)] = v[i];
  for (int s = 16; s < 4096; s <<= 1) {
    __syncthreads();
#pragma unroll
    for (int j = 0; j < 8; ++j) {
      int p = t + j * 256;
      int i = ((p & ~(s - 1)) << 1) | (p & (s - 1));
      float a = buf[SK(i)], b = buf[SK(i + s)];
      buf[SK(i)] = a + b; buf[SK(i + s)] = a - b;
    }
  }
  __syncthreads();
  const float4* sv = (const float4*)(SV + t * 16);
#pragma unroll
  for (int q = 0; q < 4; ++q) {
    float4 s = sv[q];
    float4 o;
    o.x = buf[SK(t * 16 + q * 4 + 0)] * 0.015625f * s.x;
    o.y = buf[SK(t * 16 + q * 4 + 1)] * 0.015625f * s.y;
    o.z = buf[SK(t * 16 + q * 4 + 2)] * 0.015625f * s.z;
    o.w = buf[SK(t * 16 + q * 4 + 3)] * 0.015625f * s.w;
    dp[q] = o;
  }
}

// ---------------- tgemm: Tpart[split] = h @ R_cat^T ----------------
__global__ void __launch_bounds__(256) tgemm_kernel(const bf16* __restrict__ A,
                                                    const bf16* __restrict__ Bm,
                                                    float* __restrict__ Tpart) {
  __shared__ bf16 lA[128 * 32];
  __shared__ bf16 lB[64 * 32];
  const int t = threadIdx.x, w = t >> 6, l = t & 63;
  const int bmBlk = blockIdx.x;   // 64 row blocks
  const int split = blockIdx.y;   // 4 k-splits
  const int wm = w >> 1, wn = w & 1;
  f32x4 acc[4][2] = {};
  const int arow = t >> 1, acol = (t & 1) * 16;            // A staging: 128 rows x 32
  const bf16* pa = A + (size_t)(bmBlk * 128 + arow) * KE + acol;
  const int brow = (t & 127) >> 1, bcol = acol;            // B staging: 64 rows x 32
  const bf16* pb = Bm + (size_t)brow * 4096 + bcol;
  const int fr = l & 15, fk = (l >> 4) * 8;
  for (int kt = 0; kt < 32; ++kt) {
    const int k0 = (split * 32 + kt) * 32;
    bf16x8 a0 = *(const bf16x8*)(pa + k0);
    bf16x8 a1 = *(const bf16x8*)(pa + k0 + 8);
    *(bf16x8*)&lA[arow * 32 + acol] = a0;
    *(bf16x8*)&lA[arow * 32 + acol + 8] = a1;
    if (t < 128) {
      bf16x8 b0 = *(const bf16x8*)(pb + k0);
      bf16x8 b1 = *(const bf16x8*)(pb + k0 + 8);
      *(bf16x8*)&lB[brow * 32 + bcol] = b0;
      *(bf16x8*)&lB[brow * 32 + bcol + 8] = b1;
    }
    __syncthreads();
    bf16x8 af[4], bfr[2];
#pragma unroll
    for (int i = 0; i < 4; ++i) af[i] = *(const bf16x8*)&lA[(wm * 64 + i * 16 + fr) * 32 + fk];
#pragma unroll
    for (int i = 0; i < 2; ++i) bfr[i] = *(const bf16x8*)&lB[(wn * 32 + i * 16 + fr) * 32 + fk];
#pragma unroll
    for (int mi = 0; mi < 4; ++mi)
#pragma unroll
      for (int ni = 0; ni < 2; ++ni)
        acc[mi][ni] = __builtin_amdgcn_mfma_f32_16x16x32_bf16(af[mi], bfr[ni], acc[mi][ni], 0, 0, 0);
    __syncthreads();
  }
  float* out = Tpart + (size_t)split * BB * 64;
  const int orow = bmBlk * 128 + wm * 64 + (l >> 4) * 4;
  const int ocol = wn * 32 + (l & 15);
#pragma unroll
  for (int mi = 0; mi < 4; ++mi)
#pragma unroll
    for (int ni = 0; ni < 2; ++ni)
#pragma unroll
      for (int r = 0; r < 4; ++r)
        out[(size_t)(orow + mi * 16 + r) * 64 + ocol + ni * 16] = acc[mi][ni][r];
}

__global__ void tconv_kernel(const float* __restrict__ Tpart, bf16* __restrict__ h) {
  int i = blockIdx.x * 256 + threadIdx.x;   // 8192*64
  float s = Tpart[i] + Tpart[i + BB * 64] + Tpart[i + 2 * BB * 64] + Tpart[i + 3 * BB * 64];
  int row = i >> 6, c = i & 63;
  h[(size_t)row * KE + 4096 + c] = (bf16)s;
}

// ---------------- mgemm v3: 256^2, ring-4 slots, ONE barrier per K-step ----------------
// C[8192,4096] f32 = A[8192,4160] @ B[4096,4160]^T, bf16 MFMA.
// Ring of 4 K-step slots (BK=32): sA/sB [4][256*32] bf16 = 64 KiB each.
// T2 swizzle (within a 16 KiB slot): byte ^= ((byte>>7)&3)<<4 -> measured 0
// bank conflicts (R2). Applied to the global SOURCE of global_load_lds (LDS
// dest linear, m104/m173) and to ds_read offsets (same involution, rule #21).

__device__ __forceinline__ void gload16(const void* g, void* l) {
  __builtin_amdgcn_global_load_lds(
      (const __attribute__((address_space(1))) void*)g,
      (__attribute__((address_space(3))) void*)l, 16, 0, 0);
}

__device__ __forceinline__ void bar() {
  asm volatile("" ::: "memory");
  __builtin_amdgcn_s_barrier();
  asm volatile("" ::: "memory");
}

__global__ void __launch_bounds__(512, 2) mgemm_kernel(const bf16* __restrict__ A,
                                                       const bf16* __restrict__ B,
                                                       float* __restrict__ C) {
  __shared__ alignas(16) char sA[65536];   // 4 slots x 256x32 bf16
  __shared__ alignas(16) char sB[65536];
  const int t = threadIdx.x;
  const int w = t >> 6, l = t & 63;
  const int wm = w >> 2, wn = w & 3;           // 2M x 4N waves, per-wave 128x64
  // bijective XCD swizzle (512 blocks, 512%8==0): each XCD gets 4 bm x 16 bn
  const int bid = blockIdx.x;
  const int swzb = (bid & 7) * 64 + (bid >> 3);
  const int bm = swzb >> 4, bn = swzb & 15;

  // ---- staging precompute: chunk c = w*2+j covers LDS bytes [c*1024, +1024)
  // lane l writes 16B at c*1024 + l*16 (hardware: uniform base + lane*16).
  // Pre-swizzle the SOURCE so that swizzled ds_reads see the right data.
  const int c0 = w * 2, c1 = w * 2 + 1;
  const int lb0 = c0 * 1024 + l * 16;
  const int lb1 = c1 * 1024 + l * 16;
  const int sb0 = lb0 ^ (((lb0 >> 7) & 3) << 4);
  const int sb1 = lb1 ^ (((lb1 >> 7) & 3) << 4);
  const char* gA0 = (const char*)(A + (size_t)(bm * 256 + (sb0 >> 6)) * KE) + (sb0 & 63);
  const char* gA1 = (const char*)(A + (size_t)(bm * 256 + (sb1 >> 6)) * KE) + (sb1 & 63);
  const char* gB0 = (const char*)(B + (size_t)(bn * 256 + (sb0 >> 6)) * KE) + (sb0 & 63);
  const char* gB1 = (const char*)(B + (size_t)(bn * 256 + (sb1 >> 6)) * KE) + (sb1 & 63);

  // ---- fragment ds_read byte offsets (within a 16 KiB slot), swizzled
  const int fr = l & 15, fkb = (l >> 4) * 16;  // 16x16x32 frag: row=l&15, k=(l>>4)*8 elems
  int offA[8], offB[4];
#pragma unroll
  for (int mi = 0; mi < 8; ++mi) {
    int lb = (wm * 128 + mi * 16 + fr) * 64 + fkb;
    offA[mi] = lb ^ (((lb >> 7) & 3) << 4);
  }
#pragma unroll
  for (int ni = 0; ni < 4; ++ni) {
    int lb = (wn * 64 + ni * 16 + fr) * 64 + fkb;
    offB[ni] = lb ^ (((lb >> 7) & 3) << 4);
  }

  f32x4 acc[8][4] = {};

  // ---- prologue: stage K-steps 0,1,2 (12 loads); vmcnt(8) -> slot 0 landed
#pragma unroll
  for (int p = 0; p < 3; ++p) {
    gload16(gA0 + (size_t)p * 64, &sA[p * 16384 + c0 * 1024]);
    gload16(gA1 + (size_t)p * 64, &sA[p * 16384 + c1 * 1024]);
    gload16(gB0 + (size_t)p * 64, &sB[p * 16384 + c0 * 1024]);
    gload16(gB1 + (size_t)p * 64, &sB[p * 16384 + c1 * 1024]);
  }
  asm volatile("s_waitcnt vmcnt(8)" ::: "memory");
  __builtin_amdgcn_sched_barrier(0);
  bar();

  // ---- main loop: 130 K-steps of 32; ONE barrier per K-step.
  // Iter i: stage slot (i+3)&3 (== (i-1)&3, whose reads finished before
  // bar(i-1)); read 12 frags of slot i&3; 32 MFMA; counted vmcnt; bar.
  // vmcnt(8) after staging leaves slots i+2,i+3 in flight and retires slot
  // i+1 (in-order retirement) -> after bar, slot i+1 complete collectively.
  for (int i = 0; i < 130; ++i) {
    const int sbs = (i & 3) << 14;          // current slot base
    const int s3b = ((i + 3) & 3) << 14;    // stage target slot
    const size_t ko = (size_t)(i + 3) << 6; // byte advance: 32 bf16 per K-step
    if (i < 127) {
      gload16(gA0 + ko, &sA[s3b + c0 * 1024]);
      gload16(gA1 + ko, &sA[s3b + c1 * 1024]);
      gload16(gB0 + ko, &sB[s3b + c0 * 1024]);
      gload16(gB1 + ko, &sB[s3b + c1 * 1024]);
    }
    bf16x8 af[8], bv[4];
#pragma unroll
    for (int ni = 0; ni < 4; ++ni) bv[ni] = *(const bf16x8*)&sB[sbs + offB[ni]];
#pragma unroll
    for (int mi = 0; mi < 8; ++mi) af[mi] = *(const bf16x8*)&sA[sbs + offA[mi]];
    __builtin_amdgcn_s_setprio(1);
#pragma unroll
    for (int mi = 0; mi < 8; ++mi)
#pragma unroll
      for (int ni = 0; ni < 4; ++ni)
        acc[mi][ni] = __builtin_amdgcn_mfma_f32_16x16x32_bf16(af[mi], bv[ni], acc[mi][ni], 0, 0, 0);
    __builtin_amdgcn_s_setprio(0);
    if (i < 127) {
      asm volatile("s_waitcnt vmcnt(8)" ::: "memory");   // slot i+1 landed
    } else if (i == 127) {
      asm volatile("s_waitcnt vmcnt(4)" ::: "memory");   // slot 128 landed
    } else if (i == 128) {
      asm volatile("s_waitcnt vmcnt(0)" ::: "memory");   // slot 129 landed
    }
    __builtin_amdgcn_sched_barrier(0);
    bar();
  }

  // ---- epilogue: C write (same lane->C mapping as the verified 128^2 kernel)
  const int orow = bm * 256 + wm * 128 + ((l >> 4) << 2);
  const int ocol = bn * 256 + wn * 64 + (l & 15);
#pragma unroll
  for (int mi = 0; mi < 8; ++mi)
#pragma unroll
    for (int ni = 0; ni < 4; ++ni)
#pragma unroll
      for (int r = 0; r < 4; ++r)
        C[(size_t)(orow + mi * 16 + r) * MM + ocol + ni * 16] = acc[mi][ni][r];
}

extern "C" void kernel_launch(void* const* d_in, const int* in_sizes, int n_in,
                              void* d_out, int out_size, void* d_ws, size_t ws_size,
                              hipStream_t stream) {
  const float* x    = (const float*)d_in[0];
  const float* SU   = (const float*)d_in[1];
  const float* SV   = (const float*)d_in[2];
  const float* grid = (const float*)d_in[3];
  const float* Lft  = (const float*)d_in[4];
  const float* Rft  = (const float*)d_in[5];
  const float* Lres = (const float*)d_in[6];
  const float* Rres = (const float*)d_in[7];
  const int*   qidx = (const int*)d_in[10];
  float* out = (float*)d_out;

  char* ws = (char*)d_ws;
  bf16*  h     = (bf16*)ws;                                   // 8192*4160*2 = 68,157,440
  bf16*  Wq    = (bf16*)(ws + 68157440);                      // 4096*4160*2 = 34,078,720
  bf16*  Rcat  = (bf16*)(ws + 68157440 + 34078720);           // 64*4096*2   =    524,288
  float* Tpart = (float*)(ws + 68157440 + 34078720 + 524288); // 4*8192*64*4 =  8,388,608

  prep_kernel<<<2048, 256, 0, stream>>>(Lft, Rft, Lres, Rres, Rcat, Wq);
  decode_kernel<<<8192, 256, 0, stream>>>(qidx, grid, Wq);
  fwht_pre_kernel<<<8192, 256, 0, stream>>>(x, h, SU);
  tgemm_kernel<<<dim3(64, 4), 256, 0, stream>>>(h, Rcat, Tpart);
  tconv_kernel<<<2048, 256, 0, stream>>>(Tpart, h);
  mgemm_kernel<<<512, 512, 0, stream>>>(h, Wq, out);
  fwht_post_kernel<<<8192, 256, 0, stream>>>(out, SV);
}

// Round 4
// 688.804 us; speedup vs baseline: 1.0372x; 1.0372x over previous
//
#include <hip/hip_runtime.h>
#include <hip/hip_bf16.h>
#include <stdint.h>

// LPLRQuantizedLinear: B=8192 rows, N=M=4096, rank 64 (48 frozen + 16 ft).
// ALL float tensors are FP32 (per reference); Q_idxs int32; output FP32.
//
// Pipeline:
//   prep     : R_cat[64][4096] bf16 (ws), L_cat -> Wq[:, 4096:4160] bf16
//   decode   : Wq[:, :4096] = bf16(0.02 * grid[Q_idxs])      (f32 grid)
//   fwht_pre : h[:, :4096] = bf16(FWHT(x*SU)/64)             (f32 in, fp32 math)
//   tgemm    : Tpart = h @ R_cat^T (k-split 4, fp32 partials)
//   tconv    : h[:, 4096:4160] = bf16(sum Tpart)
//   mgemm    : d_out = f32( h[8192,4160] @ Wq[4096,4160]^T ) -- 256^2 4-phase/2-K-steps
//   fwht_post: d_out = (FWHT(d_out)/64) * SV                 (f32 in-place)
//
// mgemm history: v2b (2ph/K-step, 4 bars) = 283us, MfmaUtil 43%, conflicts 0.
//   v3 (1 bar/K-step) = 350us REGRESSION: coarse 12-read->32-MFMA clusters
//   serialize (wave waits all reads, LDS floods), and vmcnt waited on loads
//   issued only ~600cyc back (HBM ~900cyc) -> stall.
// mgemm v4 = m201 discipline on v2b's verified data paths:
//   4 phases per 2 K-steps, 16 MFMA + 8/4/8/4 ds_reads per phase, ONE stage
//   unit (2 gloads) per phase, vmcnt(8) at ph1/ph3 only (waits target loads
//   issued 4 phases ~2200cyc back -> free), exact tail accounting.

typedef __bf16 bf16;
typedef __bf16 bf16x8 __attribute__((ext_vector_type(8)));
typedef float f32x4 __attribute__((ext_vector_type(4)));

#define KE 4160
#define NN 4096
#define MM 4096
#define BB 8192

// ---------------- prep: build R_cat (bf16) and L columns of Wq ----------------
__global__ void prep_kernel(const float* __restrict__ Lft, const float* __restrict__ Rft,
                            const float* __restrict__ Lres, const float* __restrict__ Rres,
                            bf16* __restrict__ Rcat, bf16* __restrict__ Wq) {
  int tid = blockIdx.x * 256 + threadIdx.x;   // 524288 total
  if (tid < 64 * 4096) {
    int r = tid >> 12, n = tid & 4095;
    float v = (r < 48) ? Rres[r * 4096 + n] : Rft[(r - 48) * 4096 + n];
    Rcat[tid] = (bf16)v;
  } else {
    int t2 = tid - 64 * 4096;
    int m = t2 >> 6, r = t2 & 63;
    float v = (r < 48) ? Lres[m * 48 + r] : Lft[m * 16 + (r - 48)];
    Wq[(size_t)m * KE + 4096 + r] = (bf16)v;
  }
}

// ---------------- decode: Wq[:, :4096] = bf16(0.02*grid[Q_idxs]) ----------------
__global__ void decode_kernel(const int* __restrict__ qidx, const float* __restrict__ grid,
                              bf16* __restrict__ Wq) {
  int tid = blockIdx.x * 256 + threadIdx.x;   // 4096*512 = 2M
  int m = tid >> 9, g = tid & 511;
  uint32_t idx = (uint32_t)qidx[tid];
  const float4* gp = (const float4*)(grid + (size_t)idx * 8);
  float4 w0 = gp[0], w1 = gp[1];
  bf16x8 o;
  o[0] = (bf16)(w0.x * 0.02f); o[1] = (bf16)(w0.y * 0.02f);
  o[2] = (bf16)(w0.z * 0.02f); o[3] = (bf16)(w0.w * 0.02f);
  o[4] = (bf16)(w1.x * 0.02f); o[5] = (bf16)(w1.y * 0.02f);
  o[6] = (bf16)(w1.z * 0.02f); o[7] = (bf16)(w1.w * 0.02f);
  *(bf16x8*)(Wq + (size_t)m * KE + g * 8) = o;
}

// ---------------- FWHT-4096 row-wise, f32 in -> bf16 out (pre, *SU before) ----------------
// (LDS skew from R2/R3 reverted: non-mgemm time went 342->365us with it --
//  the extra index VALU in the butterfly cost more than the conflicts saved.)
__global__ void fwht_pre_kernel(const float* __restrict__ src,
                                bf16* __restrict__ dst,
                                const float* __restrict__ SU) {
  __shared__ float buf[4096];
  const int row = blockIdx.x, t = threadIdx.x;
  const float4* sp = (const float4*)(src + (size_t)row * NN + t * 16);
  const float4* su = (const float4*)(SU + t * 16);
  float v[16];
#pragma unroll
  for (int q = 0; q < 4; ++q) {
    float4 a = sp[q], s = su[q];
    v[q * 4 + 0] = a.x * s.x; v[q * 4 + 1] = a.y * s.y;
    v[q * 4 + 2] = a.z * s.z; v[q * 4 + 3] = a.w * s.w;
  }
#pragma unroll
  for (int s = 1; s < 16; s <<= 1) {
#pragma unroll
    for (int i = 0; i < 16; ++i) {
      if (!(i & s)) { float a = v[i], b = v[i + s]; v[i] = a + b; v[i + s] = a - b; }
    }
  }
#pragma unroll
  for (int i = 0; i < 16; ++i) buf[t * 16 + i] = v[i];
  for (int s = 16; s < 4096; s <<= 1) {
    __syncthreads();
#pragma unroll
    for (int j = 0; j < 8; ++j) {
      int p = t + j * 256;
      int i = ((p & ~(s - 1)) << 1) | (p & (s - 1));
      float a = buf[i], b = buf[i + s];
      buf[i] = a + b; buf[i + s] = a - b;
    }
  }
  __syncthreads();
  bf16x8 o0, o1;
#pragma unroll
  for (int i = 0; i < 8; ++i) {
    o0[i] = (bf16)(buf[t * 16 + i] * 0.015625f);
    o1[i] = (bf16)(buf[t * 16 + 8 + i] * 0.015625f);
  }
  bf16* dp = dst + (size_t)row * KE + t * 16;
  *(bf16x8*)dp = o0;
  *(bf16x8*)(dp + 8) = o1;
}

// ---------------- FWHT-4096 row-wise, f32 in-place (post, *SV after) ----------------
__global__ void fwht_post_kernel(float* __restrict__ data, const float* __restrict__ SV) {
  __shared__ float buf[4096];
  const int row = blockIdx.x, t = threadIdx.x;
  float4* dp = (float4*)(data + (size_t)row * MM + t * 16);
  float v[16];
#pragma unroll
  for (int q = 0; q < 4; ++q) {
    float4 a = dp[q];
    v[q * 4 + 0] = a.x; v[q * 4 + 1] = a.y; v[q * 4 + 2] = a.z; v[q * 4 + 3] = a.w;
  }
#pragma unroll
  for (int s = 1; s < 16; s <<= 1) {
#pragma unroll
    for (int i = 0; i < 16; ++i) {
      if (!(i & s)) { float a = v[i], b = v[i + s]; v[i] = a + b; v[i + s] = a - b; }
    }
  }
#pragma unroll
  for (int i = 0; i < 16; ++i) buf[t * 16 + i] = v[i];
  for (int s = 16; s < 4096; s <<= 1) {
    __syncthreads();
#pragma unroll
    for (int j = 0; j < 8; ++j) {
      int p = t + j * 256;
      int i = ((p & ~(s - 1)) << 1) | (p & (s - 1));
      float a = buf[i], b = buf[i + s];
      buf[i] = a + b; buf[i + s] = a - b;
    }
  }
  __syncthreads();
  const float4* sv = (const float4*)(SV + t * 16);
#pragma unroll
  for (int q = 0; q < 4; ++q) {
    float4 s = sv[q];
    float4 o;
    o.x = buf[t * 16 + q * 4 + 0] * 0.015625f * s.x;
    o.y = buf[t * 16 + q * 4 + 1] * 0.015625f * s.y;
    o.z = buf[t * 16 + q * 4 + 2] * 0.015625f * s.z;
    o.w = buf[t * 16 + q * 4 + 3] * 0.015625f * s.w;
    dp[q] = o;
  }
}

// ---------------- tgemm: Tpart[split] = h @ R_cat^T ----------------
__global__ void __launch_bounds__(256) tgemm_kernel(const bf16* __restrict__ A,
                                                    const bf16* __restrict__ Bm,
                                                    float* __restrict__ Tpart) {
  __shared__ bf16 lA[128 * 32];
  __shared__ bf16 lB[64 * 32];
  const int t = threadIdx.x, w = t >> 6, l = t & 63;
  const int bmBlk = blockIdx.x;   // 64 row blocks
  const int split = blockIdx.y;   // 4 k-splits
  const int wm = w >> 1, wn = w & 1;
  f32x4 acc[4][2] = {};
  const int arow = t >> 1, acol = (t & 1) * 16;            // A staging: 128 rows x 32
  const bf16* pa = A + (size_t)(bmBlk * 128 + arow) * KE + acol;
  const int brow = (t & 127) >> 1, bcol = acol;            // B staging: 64 rows x 32
  const bf16* pb = Bm + (size_t)brow * 4096 + bcol;
  const int fr = l & 15, fk = (l >> 4) * 8;
  for (int kt = 0; kt < 32; ++kt) {
    const int k0 = (split * 32 + kt) * 32;
    bf16x8 a0 = *(const bf16x8*)(pa + k0);
    bf16x8 a1 = *(const bf16x8*)(pa + k0 + 8);
    *(bf16x8*)&lA[arow * 32 + acol] = a0;
    *(bf16x8*)&lA[arow * 32 + acol + 8] = a1;
    if (t < 128) {
      bf16x8 b0 = *(const bf16x8*)(pb + k0);
      bf16x8 b1 = *(const bf16x8*)(pb + k0 + 8);
      *(bf16x8*)&lB[brow * 32 + bcol] = b0;
      *(bf16x8*)&lB[brow * 32 + bcol + 8] = b1;
    }
    __syncthreads();
    bf16x8 af[4], bfr[2];
#pragma unroll
    for (int i = 0; i < 4; ++i) af[i] = *(const bf16x8*)&lA[(wm * 64 + i * 16 + fr) * 32 + fk];
#pragma unroll
    for (int i = 0; i < 2; ++i) bfr[i] = *(const bf16x8*)&lB[(wn * 32 + i * 16 + fr) * 32 + fk];
#pragma unroll
    for (int mi = 0; mi < 4; ++mi)
#pragma unroll
      for (int ni = 0; ni < 2; ++ni)
        acc[mi][ni] = __builtin_amdgcn_mfma_f32_16x16x32_bf16(af[mi], bfr[ni], acc[mi][ni], 0, 0, 0);
    __syncthreads();
  }
  float* out = Tpart + (size_t)split * BB * 64;
  const int orow = bmBlk * 128 + wm * 64 + (l >> 4) * 4;
  const int ocol = wn * 32 + (l & 15);
#pragma unroll
  for (int mi = 0; mi < 4; ++mi)
#pragma unroll
    for (int ni = 0; ni < 2; ++ni)
#pragma unroll
      for (int r = 0; r < 4; ++r)
        out[(size_t)(orow + mi * 16 + r) * 64 + ocol + ni * 16] = acc[mi][ni][r];
}

__global__ void tconv_kernel(const float* __restrict__ Tpart, bf16* __restrict__ h) {
  int i = blockIdx.x * 256 + threadIdx.x;   // 8192*64
  float s = Tpart[i] + Tpart[i + BB * 64] + Tpart[i + 2 * BB * 64] + Tpart[i + 3 * BB * 64];
  int row = i >> 6, c = i & 63;
  h[(size_t)row * KE + 4096 + c] = (bf16)s;
}

// ---------------- mgemm v4: 256^2, ring-4 slots, 4 phases per 2 K-steps ----------------
// C[8192,4096] f32 = A[8192,4160] @ B[4096,4160]^T, bf16 MFMA.
// Ring of 4 K-step slots (BK=32): sA/sB [4][256*32] bf16 = 64 KiB each.
// T2 swizzle (within a 16 KiB slot): byte ^= ((byte>>7)&3)<<4 -> measured 0
// bank conflicts (R2). Applied to the global SOURCE of global_load_lds (LDS
// dest linear) and to ds_read offsets (same involution both sides).
//
// Schedule per iter j (K-steps 2j, 2j+1; slots s0=(2j)&3, s1=s0+1):
//  ph0: rd A-mh0@s0 (4) + B@s0 (4); stage A(2j+3); bar; MFMA acc[0..3]; bar
//  ph1: rd A-mh1@s0 (4);            stage B(2j+3); bar; MFMA acc[4..7];
//       vmcnt(8); bar
//  ph2: rd A-mh0@s1 (4) + B@s1 (4); stage A(2j+4); bar; MFMA acc[0..3]; bar
//  ph3: rd A-mh1@s1 (4);            stage B(2j+4); bar; MFMA acc[4..7];
//       vmcnt(8); bar
// Stage-safety: A/B(2j+3) -> slot (2j-1)&3, read in iter j-1 ph2/ph3,
// complete before iter j-1's final bar. A/B(2j+4) -> slot (2j)&3, read in
// ph0/ph1 (lgkm-drained before each phase's MFMA), complete block-wide at
// ph1's end-bar; staged at ph2/ph3 after it.
// vmcnt-safety (units = 2 loads; order A0,B0,A1,B1,A2,B2 then per-phase):
//  ph1-end: staged S=4j+8 units; vmcnt(8)=4 units out -> landed h<=4j+3 =
//           K(2j+1), needed by ph2/ph3 of THIS iter.  Waited loads were
//           issued >=4 phases (~2200cyc) back -> free.
//  ph3-end: S=4j+10; vmcnt(8) -> landed h<=4j+5 = K(2j+2), needed by next
//           iter ph0/ph1.  (j=63: vmcnt(0) drains; j=64: none.)

__device__ __forceinline__ void gload16(const void* g, void* l) {
  __builtin_amdgcn_global_load_lds(
      (const __attribute__((address_space(1))) void*)g,
      (__attribute__((address_space(3))) void*)l, 16, 0, 0);
}

__device__ __forceinline__ void bar() {
  asm volatile("" ::: "memory");
  __builtin_amdgcn_s_barrier();
  asm volatile("" ::: "memory");
}

#define RD_A(half, sbs) \
  _Pragma("unroll") \
  for (int mi = 0; mi < 4; ++mi) af[mi] = *(const bf16x8*)&sA[(sbs) + offA[(half) * 4 + mi]];
#define RD_B(sbs) \
  _Pragma("unroll") \
  for (int ni = 0; ni < 4; ++ni) bv[ni] = *(const bf16x8*)&sB[(sbs) + offB[ni]];
#define MFMA16(base) \
  __builtin_amdgcn_s_setprio(1); \
  _Pragma("unroll") \
  for (int mi = 0; mi < 4; ++mi) \
    _Pragma("unroll") \
    for (int ni = 0; ni < 4; ++ni) \
      acc[(base) + mi][ni] = \
          __builtin_amdgcn_mfma_f32_16x16x32_bf16(af[mi], bv[ni], acc[(base) + mi][ni], 0, 0, 0); \
  __builtin_amdgcn_s_setprio(0);

__global__ void __launch_bounds__(512, 2) mgemm_kernel(const bf16* __restrict__ A,
                                                       const bf16* __restrict__ B,
                                                       float* __restrict__ C) {
  __shared__ alignas(16) char sA[65536];   // 4 slots x 256x32 bf16
  __shared__ alignas(16) char sB[65536];
  const int t = threadIdx.x;
  const int w = t >> 6, l = t & 63;
  const int wm = w >> 2, wn = w & 3;           // 2M x 4N waves, per-wave 128x64
  // bijective XCD swizzle (512 blocks, 512%8==0): each XCD gets 4 bm x 16 bn
  const int bid = blockIdx.x;
  const int swzb = (bid & 7) * 64 + (bid >> 3);
  const int bm = swzb >> 4, bn = swzb & 15;

  // ---- staging precompute: chunk c = w*2+j covers LDS bytes [c*1024, +1024)
  // lane l writes 16B at c*1024 + l*16 (hardware: uniform base + lane*16).
  // Pre-swizzle the SOURCE so that swizzled ds_reads see the right data.
  const int c0 = w * 2, c1 = w * 2 + 1;
  const int lb0 = c0 * 1024 + l * 16;
  const int lb1 = c1 * 1024 + l * 16;
  const int sb0 = lb0 ^ (((lb0 >> 7) & 3) << 4);
  const int sb1 = lb1 ^ (((lb1 >> 7) & 3) << 4);
  const char* gA0 = (const char*)(A + (size_t)(bm * 256 + (sb0 >> 6)) * KE) + (sb0 & 63);
  const char* gA1 = (const char*)(A + (size_t)(bm * 256 + (sb1 >> 6)) * KE) + (sb1 & 63);
  const char* gB0 = (const char*)(B + (size_t)(bn * 256 + (sb0 >> 6)) * KE) + (sb0 & 63);
  const char* gB1 = (const char*)(B + (size_t)(bn * 256 + (sb1 >> 6)) * KE) + (sb1 & 63);

  // ---- fragment ds_read byte offsets (within a 16 KiB slot), swizzled
  const int fr = l & 15, fkb = (l >> 4) * 16;  // 16x16x32 frag: row=l&15, k=(l>>4)*8 elems
  int offA[8], offB[4];
#pragma unroll
  for (int mi = 0; mi < 8; ++mi) {
    int lb = (wm * 128 + mi * 16 + fr) * 64 + fkb;
    offA[mi] = lb ^ (((lb >> 7) & 3) << 4);
  }
#pragma unroll
  for (int ni = 0; ni < 4; ++ni) {
    int lb = (wn * 64 + ni * 16 + fr) * 64 + fkb;
    offB[ni] = lb ^ (((lb >> 7) & 3) << 4);
  }

  f32x4 acc[8][4] = {};

  // ---- prologue: units A0,B0,A1,B1,A2,B2 (12 loads); vmcnt(4) -> K0,K1 landed
#pragma unroll
  for (int k = 0; k < 3; ++k) {
    gload16(gA0 + ((size_t)k << 6), &sA[(k << 14) + c0 * 1024]);
    gload16(gA1 + ((size_t)k << 6), &sA[(k << 14) + c1 * 1024]);
    gload16(gB0 + ((size_t)k << 6), &sB[(k << 14) + c0 * 1024]);
    gload16(gB1 + ((size_t)k << 6), &sB[(k << 14) + c1 * 1024]);
  }
  asm volatile("s_waitcnt vmcnt(4)" ::: "memory");
  __builtin_amdgcn_sched_barrier(0);
  bar();

  // ---- main loop: 65 iters x 2 K-steps
  for (int j = 0; j < 65; ++j) {
    const int sbs0 = (j & 1) << 15;          // slot (2j)&3 base
    const int sbs1 = sbs0 + 16384;           // slot (2j+1)&3 base
    const int k3 = 2 * j + 3, k4 = 2 * j + 4;
    const size_t ko3 = (size_t)k3 << 6, ko4 = (size_t)k4 << 6;
    const int sl3 = (k3 & 3) << 14, sl4 = (k4 & 3) << 14;
    bf16x8 af[4], bv[4];

    // ---- ph0
    RD_A(0, sbs0)
    RD_B(sbs0)
    if (j <= 63) {
      gload16(gA0 + ko3, &sA[sl3 + c0 * 1024]);
      gload16(gA1 + ko3, &sA[sl3 + c1 * 1024]);
    }
    bar();
    MFMA16(0)
    bar();

    // ---- ph1
    RD_A(1, sbs0)
    if (j <= 63) {
      gload16(gB0 + ko3, &sB[sl3 + c0 * 1024]);
      gload16(gB1 + ko3, &sB[sl3 + c1 * 1024]);
    }
    bar();
    MFMA16(4)
    if (j <= 63) {
      asm volatile("s_waitcnt vmcnt(8)" ::: "memory");
      __builtin_amdgcn_sched_barrier(0);
    }
    bar();

    // ---- ph2
    RD_A(0, sbs1)
    RD_B(sbs1)
    if (j <= 62) {
      gload16(gA0 + ko4, &sA[sl4 + c0 * 1024]);
      gload16(gA1 + ko4, &sA[sl4 + c1 * 1024]);
    }
    bar();
    MFMA16(0)
    bar();

    // ---- ph3
    RD_A(1, sbs1)
    if (j <= 62) {
      gload16(gB0 + ko4, &sB[sl4 + c0 * 1024]);
      gload16(gB1 + ko4, &sB[sl4 + c1 * 1024]);
    }
    bar();
    MFMA16(4)
    if (j <= 62) {
      asm volatile("s_waitcnt vmcnt(8)" ::: "memory");
      __builtin_amdgcn_sched_barrier(0);
    } else if (j == 63) {
      asm volatile("s_waitcnt vmcnt(0)" ::: "memory");
      __builtin_amdgcn_sched_barrier(0);
    }
    bar();
  }

  // ---- epilogue: C write (same lane->C mapping as the verified 128^2 kernel)
  const int orow = bm * 256 + wm * 128 + ((l >> 4) << 2);
  const int ocol = bn * 256 + wn * 64 + (l & 15);
#pragma unroll
  for (int mi = 0; mi < 8; ++mi)
#pragma unroll
    for (int ni = 0; ni < 4; ++ni)
#pragma unroll
      for (int r = 0; r < 4; ++r)
        C[(size_t)(orow + mi * 16 + r) * MM + ocol + ni * 16] = acc[mi][ni][r];
}

extern "C" void kernel_launch(void* const* d_in, const int* in_sizes, int n_in,
                              void* d_out, int out_size, void* d_ws, size_t ws_size,
                              hipStream_t stream) {
  const float* x    = (const float*)d_in[0];
  const float* SU   = (const float*)d_in[1];
  const float* SV   = (const float*)d_in[2];
  const float* grid = (const float*)d_in[3];
  const float* Lft  = (const float*)d_in[4];
  const float* Rft  = (const float*)d_in[5];
  const float* Lres = (const float*)d_in[6];
  const float* Rres = (const float*)d_in[7];
  const int*   qidx = (const int*)d_in[10];
  float* out = (float*)d_out;

  char* ws = (char*)d_ws;
  bf16*  h     = (bf16*)ws;                                   // 8192*4160*2 = 68,157,440
  bf16*  Wq    = (bf16*)(ws + 68157440);                      // 4096*4160*2 = 34,078,720
  bf16*  Rcat  = (bf16*)(ws + 68157440 + 34078720);           // 64*4096*2   =    524,288
  float* Tpart = (float*)(ws + 68157440 + 34078720 + 524288); // 4*8192*64*4 =  8,388,608

  prep_kernel<<<2048, 256, 0, stream>>>(Lft, Rft, Lres, Rres, Rcat, Wq);
  decode_kernel<<<8192, 256, 0, stream>>>(qidx, grid, Wq);
  fwht_pre_kernel<<<8192, 256, 0, stream>>>(x, h, SU);
  tgemm_kernel<<<dim3(64, 4), 256, 0, stream>>>(h, Rcat, Tpart);
  tconv_kernel<<<2048, 256, 0, stream>>>(Tpart, h);
  mgemm_kernel<<<512, 512, 0, stream>>>(h, Wq, out);
  fwht_post_kernel<<<8192, 256, 0, stream>>>(out, SV);
}

// Round 5
// 648.032 us; speedup vs baseline: 1.1025x; 1.0629x over previous
//
#include <hip/hip_runtime.h>
#include <hip/hip_bf16.h>
#include <stdint.h>

// LPLRQuantizedLinear: B=8192 rows, N=M=4096, rank 64 (48 frozen + 16 ft).
// ALL float tensors are FP32 (per reference); Q_idxs int32; output FP32.
//
// Pipeline:
//   prep     : R_cat[64][4096] bf16 (ws), L_cat -> Wq[:, 4096:4160] bf16
//   decode   : Wq[:, :4096] = bf16(0.02 * grid[Q_idxs])      (f32 grid)
//   fwht_pre : h[:, :4096] = bf16(FWHT(x*SU)/64)             (f32 in, fp32 math)
//   tgemm    : Tpart = h @ R_cat^T (k-split 4, fp32 partials)
//   tconv    : h[:, 4096:4160] = bf16(sum Tpart)
//   mgemm    : d_out = f32( h[8192,4160] @ Wq[4096,4160]^T ) -- 256^2 v5
//   fwht_post: d_out = (FWHT(d_out)/64) * SV                 (f32 in-place)
//
// mgemm history (measured):
//   v2b (2ph/K-step, 4 bars, vmcnt8 pre-MFMA-B bar)  = 283us, MfmaUtil 43%, confl 0  <- champion
//   v3  (1 bar/K-step, coarse 12rd->32MFMA)          = 350us REGRESSION
//   v4  (4ph/2K-steps, vmcnt after MFMA, 2x unroll)  = 334us REGRESSION
// v2b residual: 2612 cyc/K-step = reads and MFMA in disjoint barrier windows
// (768+621+384+621+bar). v5 = v2b with ONE delta: all 12 frag reads issued in
// phase A's read region. af2 (phase-B operands) drain during MFMA-A via
// compiler counted-lgkmcnt; phase B's pre-MFMA window is empty. Barriers,
// vmcnt value/placement, staging, swizzle, C-write: byte-identical to v2b.

typedef __bf16 bf16;
typedef __bf16 bf16x8 __attribute__((ext_vector_type(8)));
typedef float f32x4 __attribute__((ext_vector_type(4)));

#define KE 4160
#define NN 4096
#define MM 4096
#define BB 8192

// ---------------- prep: build R_cat (bf16) and L columns of Wq ----------------
__global__ void prep_kernel(const float* __restrict__ Lft, const float* __restrict__ Rft,
                            const float* __restrict__ Lres, const float* __restrict__ Rres,
                            bf16* __restrict__ Rcat, bf16* __restrict__ Wq) {
  int tid = blockIdx.x * 256 + threadIdx.x;   // 524288 total
  if (tid < 64 * 4096) {
    int r = tid >> 12, n = tid & 4095;
    float v = (r < 48) ? Rres[r * 4096 + n] : Rft[(r - 48) * 4096 + n];
    Rcat[tid] = (bf16)v;
  } else {
    int t2 = tid - 64 * 4096;
    int m = t2 >> 6, r = t2 & 63;
    float v = (r < 48) ? Lres[m * 48 + r] : Lft[m * 16 + (r - 48)];
    Wq[(size_t)m * KE + 4096 + r] = (bf16)v;
  }
}

// ---------------- decode: Wq[:, :4096] = bf16(0.02*grid[Q_idxs]) ----------------
__global__ void decode_kernel(const int* __restrict__ qidx, const float* __restrict__ grid,
                              bf16* __restrict__ Wq) {
  int tid = blockIdx.x * 256 + threadIdx.x;   // 4096*512 = 2M
  int m = tid >> 9, g = tid & 511;
  uint32_t idx = (uint32_t)qidx[tid];
  const float4* gp = (const float4*)(grid + (size_t)idx * 8);
  float4 w0 = gp[0], w1 = gp[1];
  bf16x8 o;
  o[0] = (bf16)(w0.x * 0.02f); o[1] = (bf16)(w0.y * 0.02f);
  o[2] = (bf16)(w0.z * 0.02f); o[3] = (bf16)(w0.w * 0.02f);
  o[4] = (bf16)(w1.x * 0.02f); o[5] = (bf16)(w1.y * 0.02f);
  o[6] = (bf16)(w1.z * 0.02f); o[7] = (bf16)(w1.w * 0.02f);
  *(bf16x8*)(Wq + (size_t)m * KE + g * 8) = o;
}

// ---------------- FWHT-4096 row-wise, f32 in -> bf16 out (pre, *SU before) ----------------
// (LDS skew experiment reverted: cost more index-VALU than the conflicts saved.)
__global__ void fwht_pre_kernel(const float* __restrict__ src,
                                bf16* __restrict__ dst,
                                const float* __restrict__ SU) {
  __shared__ float buf[4096];
  const int row = blockIdx.x, t = threadIdx.x;
  const float4* sp = (const float4*)(src + (size_t)row * NN + t * 16);
  const float4* su = (const float4*)(SU + t * 16);
  float v[16];
#pragma unroll
  for (int q = 0; q < 4; ++q) {
    float4 a = sp[q], s = su[q];
    v[q * 4 + 0] = a.x * s.x; v[q * 4 + 1] = a.y * s.y;
    v[q * 4 + 2] = a.z * s.z; v[q * 4 + 3] = a.w * s.w;
  }
#pragma unroll
  for (int s = 1; s < 16; s <<= 1) {
#pragma unroll
    for (int i = 0; i < 16; ++i) {
      if (!(i & s)) { float a = v[i], b = v[i + s]; v[i] = a + b; v[i + s] = a - b; }
    }
  }
#pragma unroll
  for (int i = 0; i < 16; ++i) buf[t * 16 + i] = v[i];
  for (int s = 16; s < 4096; s <<= 1) {
    __syncthreads();
#pragma unroll
    for (int j = 0; j < 8; ++j) {
      int p = t + j * 256;
      int i = ((p & ~(s - 1)) << 1) | (p & (s - 1));
      float a = buf[i], b = buf[i + s];
      buf[i] = a + b; buf[i + s] = a - b;
    }
  }
  __syncthreads();
  bf16x8 o0, o1;
#pragma unroll
  for (int i = 0; i < 8; ++i) {
    o0[i] = (bf16)(buf[t * 16 + i] * 0.015625f);
    o1[i] = (bf16)(buf[t * 16 + 8 + i] * 0.015625f);
  }
  bf16* dp = dst + (size_t)row * KE + t * 16;
  *(bf16x8*)dp = o0;
  *(bf16x8*)(dp + 8) = o1;
}

// ---------------- FWHT-4096 row-wise, f32 in-place (post, *SV after) ----------------
__global__ void fwht_post_kernel(float* __restrict__ data, const float* __restrict__ SV) {
  __shared__ float buf[4096];
  const int row = blockIdx.x, t = threadIdx.x;
  float4* dp = (float4*)(data + (size_t)row * MM + t * 16);
  float v[16];
#pragma unroll
  for (int q = 0; q < 4; ++q) {
    float4 a = dp[q];
    v[q * 4 + 0] = a.x; v[q * 4 + 1] = a.y; v[q * 4 + 2] = a.z; v[q * 4 + 3] = a.w;
  }
#pragma unroll
  for (int s = 1; s < 16; s <<= 1) {
#pragma unroll
    for (int i = 0; i < 16; ++i) {
      if (!(i & s)) { float a = v[i], b = v[i + s]; v[i] = a + b; v[i + s] = a - b; }
    }
  }
#pragma unroll
  for (int i = 0; i < 16; ++i) buf[t * 16 + i] = v[i];
  for (int s = 16; s < 4096; s <<= 1) {
    __syncthreads();
#pragma unroll
    for (int j = 0; j < 8; ++j) {
      int p = t + j * 256;
      int i = ((p & ~(s - 1)) << 1) | (p & (s - 1));
      float a = buf[i], b = buf[i + s];
      buf[i] = a + b; buf[i + s] = a - b;
    }
  }
  __syncthreads();
  const float4* sv = (const float4*)(SV + t * 16);
#pragma unroll
  for (int q = 0; q < 4; ++q) {
    float4 s = sv[q];
    float4 o;
    o.x = buf[t * 16 + q * 4 + 0] * 0.015625f * s.x;
    o.y = buf[t * 16 + q * 4 + 1] * 0.015625f * s.y;
    o.z = buf[t * 16 + q * 4 + 2] * 0.015625f * s.z;
    o.w = buf[t * 16 + q * 4 + 3] * 0.015625f * s.w;
    dp[q] = o;
  }
}

// ---------------- tgemm: Tpart[split] = h @ R_cat^T ----------------
__global__ void __launch_bounds__(256) tgemm_kernel(const bf16* __restrict__ A,
                                                    const bf16* __restrict__ Bm,
                                                    float* __restrict__ Tpart) {
  __shared__ bf16 lA[128 * 32];
  __shared__ bf16 lB[64 * 32];
  const int t = threadIdx.x, w = t >> 6, l = t & 63;
  const int bmBlk = blockIdx.x;   // 64 row blocks
  const int split = blockIdx.y;   // 4 k-splits
  const int wm = w >> 1, wn = w & 1;
  f32x4 acc[4][2] = {};
  const int arow = t >> 1, acol = (t & 1) * 16;            // A staging: 128 rows x 32
  const bf16* pa = A + (size_t)(bmBlk * 128 + arow) * KE + acol;
  const int brow = (t & 127) >> 1, bcol = acol;            // B staging: 64 rows x 32
  const bf16* pb = Bm + (size_t)brow * 4096 + bcol;
  const int fr = l & 15, fk = (l >> 4) * 8;
  for (int kt = 0; kt < 32; ++kt) {
    const int k0 = (split * 32 + kt) * 32;
    bf16x8 a0 = *(const bf16x8*)(pa + k0);
    bf16x8 a1 = *(const bf16x8*)(pa + k0 + 8);
    *(bf16x8*)&lA[arow * 32 + acol] = a0;
    *(bf16x8*)&lA[arow * 32 + acol + 8] = a1;
    if (t < 128) {
      bf16x8 b0 = *(const bf16x8*)(pb + k0);
      bf16x8 b1 = *(const bf16x8*)(pb + k0 + 8);
      *(bf16x8*)&lB[brow * 32 + bcol] = b0;
      *(bf16x8*)&lB[brow * 32 + bcol + 8] = b1;
    }
    __syncthreads();
    bf16x8 af[4], bfr[2];
#pragma unroll
    for (int i = 0; i < 4; ++i) af[i] = *(const bf16x8*)&lA[(wm * 64 + i * 16 + fr) * 32 + fk];
#pragma unroll
    for (int i = 0; i < 2; ++i) bfr[i] = *(const bf16x8*)&lB[(wn * 32 + i * 16 + fr) * 32 + fk];
#pragma unroll
    for (int mi = 0; mi < 4; ++mi)
#pragma unroll
      for (int ni = 0; ni < 2; ++ni)
        acc[mi][ni] = __builtin_amdgcn_mfma_f32_16x16x32_bf16(af[mi], bfr[ni], acc[mi][ni], 0, 0, 0);
    __syncthreads();
  }
  float* out = Tpart + (size_t)split * BB * 64;
  const int orow = bmBlk * 128 + wm * 64 + (l >> 4) * 4;
  const int ocol = wn * 32 + (l & 15);
#pragma unroll
  for (int mi = 0; mi < 4; ++mi)
#pragma unroll
    for (int ni = 0; ni < 2; ++ni)
#pragma unroll
      for (int r = 0; r < 4; ++r)
        out[(size_t)(orow + mi * 16 + r) * 64 + ocol + ni * 16] = acc[mi][ni][r];
}

__global__ void tconv_kernel(const float* __restrict__ Tpart, bf16* __restrict__ h) {
  int i = blockIdx.x * 256 + threadIdx.x;   // 8192*64
  float s = Tpart[i] + Tpart[i + BB * 64] + Tpart[i + 2 * BB * 64] + Tpart[i + 3 * BB * 64];
  int row = i >> 6, c = i & 63;
  h[(size_t)row * KE + 4096 + c] = (bf16)s;
}

// ---------------- mgemm v5: v2b skeleton + hoisted phase-B reads ----------------
// C[8192,4096] f32 = A[8192,4160] @ B[4096,4160]^T, bf16 MFMA.
// Ring of 4 K-step slots (BK=32): sA/sB [4][256*32] bf16 = 64 KiB each.
// T2 swizzle (within a 16 KiB slot): byte ^= ((byte>>7)&3)<<4 -> measured 0
// bank conflicts (R2). Applied to the global SOURCE of global_load_lds (LDS
// dest linear) and to ds_read offsets (same involution both sides).
// Schedule per K-step i (identical to v2b except af2 reads hoisted):
//  phA: rd af[0..3], bv[0..3], af2[0..3] (12 ds_read_b128); stage A(i+3);
//       bar; MFMA acc[0..3](af,bv); bar
//  phB: stage B(i+3); vmcnt(8); bar; MFMA acc[4..7](af2,bv); bar
// af2 drains during MFMA-A (compiler counted lgkmcnt); phB pre-MFMA empty.
// vmcnt(8): steady state 12 outstanding -> retires iter i-1's 4 stage loads
// -> slot i+1 landed block-wide after the following barrier (as in v2b).

__device__ __forceinline__ void gload16(const void* g, void* l) {
  __builtin_amdgcn_global_load_lds(
      (const __attribute__((address_space(1))) void*)g,
      (__attribute__((address_space(3))) void*)l, 16, 0, 0);
}

__device__ __forceinline__ void bar() {
  asm volatile("" ::: "memory");
  __builtin_amdgcn_s_barrier();
  asm volatile("" ::: "memory");
}

__global__ void __launch_bounds__(512, 2) mgemm_kernel(const bf16* __restrict__ A,
                                                       const bf16* __restrict__ B,
                                                       float* __restrict__ C) {
  __shared__ alignas(16) char sA[65536];   // 4 slots x 256x32 bf16
  __shared__ alignas(16) char sB[65536];
  const int t = threadIdx.x;
  const int w = t >> 6, l = t & 63;
  const int wm = w >> 2, wn = w & 3;           // 2M x 4N waves, per-wave 128x64
  // bijective XCD swizzle (512 blocks, 512%8==0): each XCD gets 4 bm x 16 bn
  const int bid = blockIdx.x;
  const int swzb = (bid & 7) * 64 + (bid >> 3);
  const int bm = swzb >> 4, bn = swzb & 15;

  // ---- staging precompute: chunk c = w*2+j covers LDS bytes [c*1024, +1024)
  // lane l writes 16B at c*1024 + l*16 (hardware: uniform base + lane*16).
  // Pre-swizzle the SOURCE so that swizzled ds_reads see the right data.
  const int c0 = w * 2, c1 = w * 2 + 1;
  const int lb0 = c0 * 1024 + l * 16;
  const int lb1 = c1 * 1024 + l * 16;
  const int sb0 = lb0 ^ (((lb0 >> 7) & 3) << 4);
  const int sb1 = lb1 ^ (((lb1 >> 7) & 3) << 4);
  const char* gA0 = (const char*)(A + (size_t)(bm * 256 + (sb0 >> 6)) * KE) + (sb0 & 63);
  const char* gA1 = (const char*)(A + (size_t)(bm * 256 + (sb1 >> 6)) * KE) + (sb1 & 63);
  const char* gB0 = (const char*)(B + (size_t)(bn * 256 + (sb0 >> 6)) * KE) + (sb0 & 63);
  const char* gB1 = (const char*)(B + (size_t)(bn * 256 + (sb1 >> 6)) * KE) + (sb1 & 63);

  // ---- fragment ds_read byte offsets (within a 16 KiB slot), swizzled
  const int fr = l & 15, fkb = (l >> 4) * 16;  // 16x16x32 frag: row=l&15, k=(l>>4)*8 elems
  int offA[8], offB[4];
#pragma unroll
  for (int mi = 0; mi < 8; ++mi) {
    int lb = (wm * 128 + mi * 16 + fr) * 64 + fkb;
    offA[mi] = lb ^ (((lb >> 7) & 3) << 4);
  }
#pragma unroll
  for (int ni = 0; ni < 4; ++ni) {
    int lb = (wn * 64 + ni * 16 + fr) * 64 + fkb;
    offB[ni] = lb ^ (((lb >> 7) & 3) << 4);
  }

  f32x4 acc[8][4] = {};

  // ---- prologue: stage K-steps 0,1,2 (12 loads); vmcnt(8) -> slot 0 landed
#pragma unroll
  for (int p = 0; p < 3; ++p) {
    gload16(gA0 + (size_t)p * 64, &sA[p * 16384 + c0 * 1024]);
    gload16(gA1 + (size_t)p * 64, &sA[p * 16384 + c1 * 1024]);
    gload16(gB0 + (size_t)p * 64, &sB[p * 16384 + c0 * 1024]);
    gload16(gB1 + (size_t)p * 64, &sB[p * 16384 + c1 * 1024]);
  }
  asm volatile("s_waitcnt vmcnt(8)" ::: "memory");
  __builtin_amdgcn_sched_barrier(0);
  bar();

  // ---- main loop: 130 K-steps of 32; v2b barrier skeleton
  for (int i = 0; i < 130; ++i) {
    const int sbs = (i & 3) << 14;          // current slot base
    const int s3b = ((i + 3) & 3) << 14;    // stage target slot (consumed at i-1)
    const size_t ko = (size_t)(i + 3) << 6; // byte advance: 32 bf16 per K-step
    bf16x8 af[4], af2[4], bv[4];
    // phase A: ALL 12 frag reads; stage A(i+3)
#pragma unroll
    for (int mi = 0; mi < 4; ++mi) af[mi] = *(const bf16x8*)&sA[sbs + offA[mi]];
#pragma unroll
    for (int ni = 0; ni < 4; ++ni) bv[ni] = *(const bf16x8*)&sB[sbs + offB[ni]];
#pragma unroll
    for (int mi = 0; mi < 4; ++mi) af2[mi] = *(const bf16x8*)&sA[sbs + offA[4 + mi]];
    if (i < 127) {
      gload16(gA0 + ko, &sA[s3b + c0 * 1024]);
      gload16(gA1 + ko, &sA[s3b + c1 * 1024]);
    }
    bar();
    __builtin_amdgcn_s_setprio(1);
#pragma unroll
    for (int mi = 0; mi < 4; ++mi)
#pragma unroll
      for (int ni = 0; ni < 4; ++ni)
        acc[mi][ni] = __builtin_amdgcn_mfma_f32_16x16x32_bf16(af[mi], bv[ni], acc[mi][ni], 0, 0, 0);
    __builtin_amdgcn_s_setprio(0);
    bar();
    // phase B: no reads; stage B(i+3); counted vmcnt (never 0 in-loop)
    if (i < 127) {
      gload16(gB0 + ko, &sB[s3b + c0 * 1024]);
      gload16(gB1 + ko, &sB[s3b + c1 * 1024]);
      asm volatile("s_waitcnt vmcnt(8)" ::: "memory");  // slot i+1 landed
      __builtin_amdgcn_sched_barrier(0);
    } else if (i == 127) {
      asm volatile("s_waitcnt vmcnt(4)" ::: "memory");  // slot 128 landed
      __builtin_amdgcn_sched_barrier(0);
    } else if (i == 128) {
      asm volatile("s_waitcnt vmcnt(0)" ::: "memory");  // slot 129 landed
      __builtin_amdgcn_sched_barrier(0);
    }
    bar();
    __builtin_amdgcn_s_setprio(1);
#pragma unroll
    for (int mi = 0; mi < 4; ++mi)
#pragma unroll
      for (int ni = 0; ni < 4; ++ni)
        acc[4 + mi][ni] = __builtin_amdgcn_mfma_f32_16x16x32_bf16(af2[mi], bv[ni], acc[4 + mi][ni], 0, 0, 0);
    __builtin_amdgcn_s_setprio(0);
    bar();
  }

  // ---- epilogue: C write (same lane->C mapping as the verified 128^2 kernel)
  const int orow = bm * 256 + wm * 128 + ((l >> 4) << 2);
  const int ocol = bn * 256 + wn * 64 + (l & 15);
#pragma unroll
  for (int mi = 0; mi < 8; ++mi)
#pragma unroll
    for (int ni = 0; ni < 4; ++ni)
#pragma unroll
      for (int r = 0; r < 4; ++r)
        C[(size_t)(orow + mi * 16 + r) * MM + ocol + ni * 16] = acc[mi][ni][r];
}

extern "C" void kernel_launch(void* const* d_in, const int* in_sizes, int n_in,
                              void* d_out, int out_size, void* d_ws, size_t ws_size,
                              hipStream_t stream) {
  const float* x    = (const float*)d_in[0];
  const float* SU   = (const float*)d_in[1];
  const float* SV   = (const float*)d_in[2];
  const float* grid = (const float*)d_in[3];
  const float* Lft  = (const float*)d_in[4];
  const float* Rft  = (const float*)d_in[5];
  const float* Lres = (const float*)d_in[6];
  const float* Rres = (const float*)d_in[7];
  const int*   qidx = (const int*)d_in[10];
  float* out = (float*)d_out;

  char* ws = (char*)d_ws;
  bf16*  h     = (bf16*)ws;                                   // 8192*4160*2 = 68,157,440
  bf16*  Wq    = (bf16*)(ws + 68157440);                      // 4096*4160*2 = 34,078,720
  bf16*  Rcat  = (bf16*)(ws + 68157440 + 34078720);           // 64*4096*2   =    524,288
  float* Tpart = (float*)(ws + 68157440 + 34078720 + 524288); // 4*8192*64*4 =  8,388,608

  prep_kernel<<<2048, 256, 0, stream>>>(Lft, Rft, Lres, Rres, Rcat, Wq);
  decode_kernel<<<8192, 256, 0, stream>>>(qidx, grid, Wq);
  fwht_pre_kernel<<<8192, 256, 0, stream>>>(x, h, SU);
  tgemm_kernel<<<dim3(64, 4), 256, 0, stream>>>(h, Rcat, Tpart);
  tconv_kernel<<<2048, 256, 0, stream>>>(Tpart, h);
  mgemm_kernel<<<512, 512, 0, stream>>>(h, Wq, out);
  fwht_post_kernel<<<8192, 256, 0, stream>>>(out, SV);
}